// Round 3
// baseline (269.126 us; speedup 1.0000x reference)
//
#include <hip/hip_runtime.h>
#include <math.h>

#define NB 11
#define PAD 5
#define DIM 128
#define NN 121        // NB*NB
#define S_TOT 484     // HEADS*NN
#define KHALF 242
#define IMG 64
#define TILE 4        // pixels per block (x-contiguous)
#define LN_EPS 1e-5f

__global__ __launch_bounds__(256, 8) void nca_kernel(
    const float* __restrict__ q, const float* __restrict__ kv,
    const float* __restrict__ pos, const float* __restrict__ w,
    const float* __restrict__ bias, const float* __restrict__ gam,
    const float* __restrict__ bet, float* __restrict__ out)
{
    const int tile = blockIdx.x;         // 2048 tiles of 4 pixels along x
    const int pix0 = tile * TILE;
    const int x0 = pix0 & 63;
    const int y  = (pix0 >> 6) & 63;
    const int b  = pix0 >> 12;
    const int tid = threadIdx.x;

    __shared__ float qs[TILE][DIM];      // q, later x = q + gelu(mlp)
    __shared__ float sc[TILE][S_TOT];    // scores

    // ---- stage q for 4 pixels (2 KB, coalesced) ----
    for (int i = tid; i < TILE * DIM; i += 256)
        qs[i >> 7][i & 127] = q[(size_t)pix0 * DIM + i];
    __syncthreads();

    // ---- scores: s = h*121 + n; kv slice cell p=s>>2, chans (s&3)*32.. ----
    const float* kvb = kv + (size_t)b * IMG * IMG * DIM;
    for (int it = tid; it < TILE * S_TOT; it += 256) {
        const int pix = it / S_TOT;
        const int s   = it - pix * S_TOT;
        const int p = s >> 2, r = s & 3;
        const int i = p / NB, j = p - i * NB;
        const int yy = y + i - PAD, xx = x0 + pix + j - PAD;
        const int h = s / NN;
        const float4* pe = (const float4*)(pos + (size_t)p * DIM + r * 32);
        const float4* qp = (const float4*)(&qs[pix][h * 32]);
        float acc = 0.f;
        if (((unsigned)yy < (unsigned)IMG) && ((unsigned)xx < (unsigned)IMG)) {
            const float4* kp = (const float4*)(kvb + ((size_t)(yy * IMG + xx)) * DIM + r * 32);
            #pragma unroll
            for (int d = 0; d < 8; ++d) {
                const float4 kq = kp[d], pv = pe[d], qv = qp[d];
                acc += (kq.x + pv.x) * qv.x + (kq.y + pv.y) * qv.y
                     + (kq.z + pv.z) * qv.z + (kq.w + pv.w) * qv.w;
            }
        } else {
            #pragma unroll
            for (int d = 0; d < 8; ++d) {
                const float4 pv = pe[d], qv = qp[d];
                acc += pv.x * qv.x + pv.y * qv.y + pv.z * qv.z + pv.w * qv.w;
            }
        }
        sc[pix][s] = acc;
    }
    __syncthreads();

    // ---- MLP: wave = pixel; lane = (half = lane>>5, cq = lane&31) ----
    // thread computes channels 4cq..4cq+3 over K-half [half*242, +242),
    // halves combined with shfl_xor(32).
    const int lane = tid & 63, wid = tid >> 6;   // wid = pixel 0..3
    const int cq   = lane & 31;
    const int half = lane >> 5;
    {
        const float* wp = w + (size_t)(half * KHALF) * DIM + 4 * cq;
        const float* sp = sc[wid] + half * KHALF;
        float ax = 0.f, ay = 0.f, az = 0.f, aw = 0.f;
        #pragma unroll 4
        for (int s = 0; s < KHALF; ++s) {
            const float sv = sp[s];                              // LDS broadcast
            const float4 wv = *(const float4*)(wp + (size_t)s * DIM); // 16B coalesced
            ax += sv * wv.x; ay += sv * wv.y;
            az += sv * wv.z; aw += sv * wv.w;
        }
        ax += __shfl_xor(ax, 32, 64);
        ay += __shfl_xor(ay, 32, 64);
        az += __shfl_xor(az, 32, 64);
        aw += __shfl_xor(aw, 32, 64);
        if (half == 0) {
            const float k = 0.70710678118654752f;
            const int c0 = 4 * cq;
            float v[4] = {ax + bias[c0], ay + bias[c0 + 1],
                          az + bias[c0 + 2], aw + bias[c0 + 3]};
            #pragma unroll
            for (int kk = 0; kk < 4; ++kk) {
                const float g = 0.5f * v[kk] * (1.f + erff(v[kk] * k));
                qs[wid][c0 + kk] += g;           // x = q + gelu(mlp)
            }
        }
    }
    __syncthreads();

    // ---- LayerNorm: wave wid owns pixel wid ----
    {
        const float v0 = qs[wid][lane], v1 = qs[wid][lane + 64];
        float sum = v0 + v1;
        #pragma unroll
        for (int off = 1; off < 64; off <<= 1) sum += __shfl_xor(sum, off, 64);
        const float mean = sum * (1.f / 128.f);
        const float d0 = v0 - mean, d1 = v1 - mean;
        float sq = d0 * d0 + d1 * d1;
        #pragma unroll
        for (int off = 1; off < 64; off <<= 1) sq += __shfl_xor(sq, off, 64);
        const float rstd = rsqrtf(sq * (1.f / 128.f) + LN_EPS);
        float* op = out + (size_t)(pix0 + wid) * DIM;
        op[lane]      = d0 * rstd * gam[lane]      + bet[lane];
        op[lane + 64] = d1 * rstd * gam[lane + 64] + bet[lane + 64];
    }
}

extern "C" void kernel_launch(void* const* d_in, const int* in_sizes, int n_in,
                              void* d_out, int out_size, void* d_ws, size_t ws_size,
                              hipStream_t stream) {
    const float* q    = (const float*)d_in[0];
    const float* kv   = (const float*)d_in[1];
    const float* pos  = (const float*)d_in[2];
    const float* w    = (const float*)d_in[3];
    const float* bias = (const float*)d_in[4];
    const float* gam  = (const float*)d_in[5];
    const float* bet  = (const float*)d_in[6];
    float* out = (float*)d_out;

    const int n_blocks = 2 * IMG * IMG / TILE;   // 2048
    nca_kernel<<<n_blocks, 256, 0, stream>>>(q, kv, pos, w, bias, gam, bet, out);
}

// Round 4
// 234.732 us; speedup vs baseline: 1.1465x; 1.1465x over previous
//
#include <hip/hip_runtime.h>
#include <math.h>

#define NB 11
#define PAD 5
#define DIM 128
#define NN 121        // NB*NB
#define S_TOT 484     // HEADS*NN
#define KHALF 242
#define IMG 64
#define TILE 8        // pixels per block (x-contiguous)
#define LN_EPS 1e-5f

__global__ __launch_bounds__(512, 8) void nca_kernel(
    const float* __restrict__ q, const float* __restrict__ kv,
    const float* __restrict__ pos, const float* __restrict__ w,
    const float* __restrict__ bias, const float* __restrict__ gam,
    const float* __restrict__ bet, float* __restrict__ out)
{
    const int tile = blockIdx.x;         // 1024 tiles of 8 pixels along x
    const int pix0 = tile * TILE;
    const int x0 = pix0 & 63;
    const int y  = (pix0 >> 6) & 63;
    const int b  = pix0 >> 12;
    const int tid = threadIdx.x;

    __shared__ float qs[TILE][DIM];      // q, later x = q + gelu(mlp)
    __shared__ float sc[TILE][S_TOT];    // scores
    __shared__ float part[TILE][DIM];    // K-half partial sums

    // ---- stage q for 8 pixels (4 KB, coalesced) ----
    for (int i = tid; i < TILE * DIM; i += 512)
        qs[i >> 7][i & 127] = q[(size_t)pix0 * DIM + i];
    __syncthreads();

    // ---- scores: s = h*121 + n; kv slice cell p=s>>2, chans (s&3)*32.. ----
    const float* kvb = kv + (size_t)b * IMG * IMG * DIM;
    for (int it = tid; it < TILE * S_TOT; it += 512) {
        const int pix = it / S_TOT;
        const int s   = it - pix * S_TOT;
        const int p = s >> 2, r = s & 3;
        const int i = p / NB, j = p - i * NB;
        const int yy = y + i - PAD, xx = x0 + pix + j - PAD;
        const int h = s / NN;
        const float4* pe = (const float4*)(pos + (size_t)p * DIM + r * 32);
        const float4* qp = (const float4*)(&qs[pix][h * 32]);
        float acc = 0.f;
        if (((unsigned)yy < (unsigned)IMG) && ((unsigned)xx < (unsigned)IMG)) {
            const float4* kp = (const float4*)(kvb + ((size_t)(yy * IMG + xx)) * DIM + r * 32);
            #pragma unroll
            for (int d = 0; d < 8; ++d) {
                const float4 kq = kp[d], pv = pe[d], qv = qp[d];
                acc += (kq.x + pv.x) * qv.x + (kq.y + pv.y) * qv.y
                     + (kq.z + pv.z) * qv.z + (kq.w + pv.w) * qv.w;
            }
        } else {
            #pragma unroll
            for (int d = 0; d < 8; ++d) {
                const float4 pv = pe[d], qv = qp[d];
                acc += pv.x * qv.x + pv.y * qv.y + pv.z * qv.z + pv.w * qv.w;
            }
        }
        sc[pix][s] = acc;
    }
    __syncthreads();

    // ---- MLP: thread = (channel c, g); g = (K-half ph, pixel-quad pp) ----
    // 4 accumulator chains (4 pixels), scalar coalesced w loads (256B/wave).
    const int c  = tid & 127;
    const int g  = tid >> 7;             // 0..3
    const int ph = g & 1;                // K-half
    const int pp = g >> 1;               // pixel quad: pixels pp*4..pp*4+3
    {
        const float* wc = w + (size_t)(ph * KHALF) * DIM + c;
        const float* s0 = sc[pp * 4 + 0] + ph * KHALF;
        const float* s1 = sc[pp * 4 + 1] + ph * KHALF;
        const float* s2 = sc[pp * 4 + 2] + ph * KHALF;
        const float* s3 = sc[pp * 4 + 3] + ph * KHALF;
        float a0 = 0.f, a1 = 0.f, a2 = 0.f, a3 = 0.f;
        #pragma unroll 4
        for (int s = 0; s < KHALF; ++s) {
            const float wv = wc[(size_t)s * DIM];   // coalesced scalar load
            a0 += s0[s] * wv;                       // LDS broadcasts
            a1 += s1[s] * wv;
            a2 += s2[s] * wv;
            a3 += s3[s] * wv;
        }
        if (ph == 1) {
            part[pp * 4 + 0][c] = a0;
            part[pp * 4 + 1][c] = a1;
            part[pp * 4 + 2][c] = a2;
            part[pp * 4 + 3][c] = a3;
        }
        __syncthreads();
        if (ph == 0) {
            const float k = 0.70710678118654752f;
            const float bv = bias[c];
            float v[4] = {a0 + part[pp * 4 + 0][c] + bv,
                          a1 + part[pp * 4 + 1][c] + bv,
                          a2 + part[pp * 4 + 2][c] + bv,
                          a3 + part[pp * 4 + 3][c] + bv};
            #pragma unroll
            for (int kk = 0; kk < 4; ++kk) {
                const float gl = 0.5f * v[kk] * (1.f + erff(v[kk] * k));
                qs[pp * 4 + kk][c] += gl;           // x = q + gelu(mlp)
            }
        }
    }
    __syncthreads();

    // ---- LayerNorm: wave wid owns pixel wid (8 waves, 8 pixels) ----
    {
        const int lane = tid & 63, wid = tid >> 6;
        const float v0 = qs[wid][lane], v1 = qs[wid][lane + 64];
        float sum = v0 + v1;
        #pragma unroll
        for (int off = 1; off < 64; off <<= 1) sum += __shfl_xor(sum, off, 64);
        const float mean = sum * (1.f / 128.f);
        const float d0 = v0 - mean, d1 = v1 - mean;
        float sq = d0 * d0 + d1 * d1;
        #pragma unroll
        for (int off = 1; off < 64; off <<= 1) sq += __shfl_xor(sq, off, 64);
        const float rstd = rsqrtf(sq * (1.f / 128.f) + LN_EPS);
        float* op = out + (size_t)(pix0 + wid) * DIM;
        op[lane]      = d0 * rstd * gam[lane]      + bet[lane];
        op[lane + 64] = d1 * rstd * gam[lane + 64] + bet[lane + 64];
    }
}

extern "C" void kernel_launch(void* const* d_in, const int* in_sizes, int n_in,
                              void* d_out, int out_size, void* d_ws, size_t ws_size,
                              hipStream_t stream) {
    const float* q    = (const float*)d_in[0];
    const float* kv   = (const float*)d_in[1];
    const float* pos  = (const float*)d_in[2];
    const float* w    = (const float*)d_in[3];
    const float* bias = (const float*)d_in[4];
    const float* gam  = (const float*)d_in[5];
    const float* bet  = (const float*)d_in[6];
    float* out = (float*)d_out;

    const int n_blocks = 2 * IMG * IMG / TILE;   // 1024
    nca_kernel<<<n_blocks, 512, 0, stream>>>(q, kv, pos, w, bias, gam, bet, out);
}

// Round 5
// 215.763 us; speedup vs baseline: 1.2473x; 1.0879x over previous
//
#include <hip/hip_runtime.h>
#include <math.h>

#define NB 11
#define PAD 5
#define DIM 128
#define NN 121        // NB*NB
#define S_TOT 484     // HEADS*NN
#define KHALF 242
#define IMG 64
#define TILE 8        // pixels per block (x-contiguous)
#define LN_EPS 1e-5f

// NOTE: single-arg launch bounds ONLY. (512,8)/(256,8) made the allocator cap
// at 32 VGPR and spill to scratch (WRITE_SIZE 28-37 MB vs 4 MB ideal).
__global__ __launch_bounds__(512) void nca_kernel(
    const float* __restrict__ q, const float* __restrict__ kv,
    const float* __restrict__ pos, const float* __restrict__ w,
    const float* __restrict__ bias, const float* __restrict__ gam,
    const float* __restrict__ bet, float* __restrict__ out)
{
    const int tile = blockIdx.x;         // 1024 tiles of 8 pixels along x
    const int pix0 = tile * TILE;
    const int x0 = pix0 & 63;
    const int y  = (pix0 >> 6) & 63;
    const int b  = pix0 >> 12;
    const int tid = threadIdx.x;

    __shared__ float qs[TILE][DIM];      // q, later x = q + gelu(mlp)
    __shared__ float sc[TILE][S_TOT];    // scores
    __shared__ float part[TILE][DIM];    // K-half partial sums

    // ---- stage q for 8 pixels (4 KB, coalesced) ----
    for (int i = tid; i < TILE * DIM; i += 512)
        qs[i >> 7][i & 127] = q[(size_t)pix0 * DIM + i];
    __syncthreads();

    // ---- scores: s = h*121 + n; kv slice cell p=s>>2, chans (s&3)*32.. ----
    const float* kvb = kv + (size_t)b * IMG * IMG * DIM;
    for (int it = tid; it < TILE * S_TOT; it += 512) {
        const int pix = it / S_TOT;
        const int s   = it - pix * S_TOT;
        const int p = s >> 2, r = s & 3;
        const int i = p / NB, j = p - i * NB;
        const int yy = y + i - PAD, xx = x0 + pix + j - PAD;
        const int h = s / NN;
        const float4* pe = (const float4*)(pos + (size_t)p * DIM + r * 32);
        const float4* qp = (const float4*)(&qs[pix][h * 32]);
        float acc = 0.f;
        if (((unsigned)yy < (unsigned)IMG) && ((unsigned)xx < (unsigned)IMG)) {
            const float4* kp = (const float4*)(kvb + ((size_t)(yy * IMG + xx)) * DIM + r * 32);
            #pragma unroll
            for (int d = 0; d < 8; ++d) {
                const float4 kq = kp[d], pv = pe[d], qv = qp[d];
                acc += (kq.x + pv.x) * qv.x + (kq.y + pv.y) * qv.y
                     + (kq.z + pv.z) * qv.z + (kq.w + pv.w) * qv.w;
            }
        } else {
            #pragma unroll
            for (int d = 0; d < 8; ++d) {
                const float4 pv = pe[d], qv = qp[d];
                acc += pv.x * qv.x + pv.y * qv.y + pv.z * qv.z + pv.w * qv.w;
            }
        }
        sc[pix][s] = acc;
    }
    __syncthreads();

    // ---- MLP: thread = (channel c, g); g = (K-half ph, pixel-quad pp) ----
    // 4 accumulator chains (4 pixels), scalar coalesced w loads (256B/wave).
    const int c  = tid & 127;
    const int g  = tid >> 7;             // 0..3
    const int ph = g & 1;                // K-half
    const int pp = g >> 1;               // pixel quad: pixels pp*4..pp*4+3
    {
        const float* wc = w + (size_t)(ph * KHALF) * DIM + c;
        const float* s0 = sc[pp * 4 + 0] + ph * KHALF;
        const float* s1 = sc[pp * 4 + 1] + ph * KHALF;
        const float* s2 = sc[pp * 4 + 2] + ph * KHALF;
        const float* s3 = sc[pp * 4 + 3] + ph * KHALF;
        float a0 = 0.f, a1 = 0.f, a2 = 0.f, a3 = 0.f;
        #pragma unroll 4
        for (int s = 0; s < KHALF; ++s) {
            const float wv = wc[(size_t)s * DIM];   // coalesced scalar load
            a0 += s0[s] * wv;                       // LDS broadcasts
            a1 += s1[s] * wv;
            a2 += s2[s] * wv;
            a3 += s3[s] * wv;
        }
        if (ph == 1) {
            part[pp * 4 + 0][c] = a0;
            part[pp * 4 + 1][c] = a1;
            part[pp * 4 + 2][c] = a2;
            part[pp * 4 + 3][c] = a3;
        }
        __syncthreads();
        if (ph == 0) {
            const float k = 0.70710678118654752f;
            const float bv = bias[c];
            float v[4] = {a0 + part[pp * 4 + 0][c] + bv,
                          a1 + part[pp * 4 + 1][c] + bv,
                          a2 + part[pp * 4 + 2][c] + bv,
                          a3 + part[pp * 4 + 3][c] + bv};
            #pragma unroll
            for (int kk = 0; kk < 4; ++kk) {
                const float gl = 0.5f * v[kk] * (1.f + erff(v[kk] * k));
                qs[pp * 4 + kk][c] += gl;           // x = q + gelu(mlp)
            }
        }
    }
    __syncthreads();

    // ---- LayerNorm: wave wid owns pixel wid (8 waves, 8 pixels) ----
    {
        const int lane = tid & 63, wid = tid >> 6;
        const float v0 = qs[wid][lane], v1 = qs[wid][lane + 64];
        float sum = v0 + v1;
        #pragma unroll
        for (int off = 1; off < 64; off <<= 1) sum += __shfl_xor(sum, off, 64);
        const float mean = sum * (1.f / 128.f);
        const float d0 = v0 - mean, d1 = v1 - mean;
        float sq = d0 * d0 + d1 * d1;
        #pragma unroll
        for (int off = 1; off < 64; off <<= 1) sq += __shfl_xor(sq, off, 64);
        const float rstd = rsqrtf(sq * (1.f / 128.f) + LN_EPS);
        float* op = out + (size_t)(pix0 + wid) * DIM;
        op[lane]      = d0 * rstd * gam[lane]      + bet[lane];
        op[lane + 64] = d1 * rstd * gam[lane + 64] + bet[lane + 64];
    }
}

extern "C" void kernel_launch(void* const* d_in, const int* in_sizes, int n_in,
                              void* d_out, int out_size, void* d_ws, size_t ws_size,
                              hipStream_t stream) {
    const float* q    = (const float*)d_in[0];
    const float* kv   = (const float*)d_in[1];
    const float* pos  = (const float*)d_in[2];
    const float* w    = (const float*)d_in[3];
    const float* bias = (const float*)d_in[4];
    const float* gam  = (const float*)d_in[5];
    const float* bet  = (const float*)d_in[6];
    float* out = (float*)d_out;

    const int n_blocks = 2 * IMG * IMG / TILE;   // 1024
    nca_kernel<<<n_blocks, 512, 0, stream>>>(q, kv, pos, w, bias, gam, bet, out);
}

// Round 6
// 136.961 us; speedup vs baseline: 1.9650x; 1.5754x over previous
//
#include <hip/hip_runtime.h>
#include <math.h>

#define NB 11
#define PAD 5
#define DIM 128
#define NN 121        // NB*NB
#define S_TOT 484     // HEADS*NN
#define IMG 64
#define TILE 8        // pixels per block (x-contiguous)
#define LN_EPS 1e-5f

// Single-arg launch bounds ONLY: (512,8)/(256,8) capped VGPR at 32 and spilled
// (WRITE_SIZE 28-37 MB). With 48-64 VGPR we still fit 4 blocks/CU (32 waves).
__global__ __launch_bounds__(512) void nca_kernel(
    const float* __restrict__ q, const float* __restrict__ kv,
    const float* __restrict__ pos, const float* __restrict__ w,
    const float* __restrict__ bias, const float* __restrict__ gam,
    const float* __restrict__ bet, float* __restrict__ out)
{
    const int tile = blockIdx.x;         // 1024 tiles of 8 pixels along x
    const int pix0 = tile * TILE;
    const int x0 = pix0 & 63;
    const int y  = (pix0 >> 6) & 63;
    const int b  = pix0 >> 12;
    const int tid = threadIdx.x;

    __shared__ float qs[TILE][DIM];      // q, later x = q + gelu(mlp)
    __shared__ float sc[S_TOT][TILE];    // scores, TRANSPOSED (s-major)
    __shared__ float part[4][TILE][DIM]; // per-K-group partial sums

    // ---- stage q for 8 pixels (4 KB, coalesced) ----
    for (int i = tid; i < TILE * DIM; i += 512)
        qs[i >> 7][i & 127] = q[(size_t)pix0 * DIM + i];
    __syncthreads();

    // ---- phase A: scores, row-oriented ----
    // task T = p*8 + pix; one half-wave (32 lanes x float4) = one kv row
    // (512 B coalesced; the wave's 2 half-waves are adjacent pixels -> 1 KB).
    // lane l holds chans c=4l..4l+3; r = c/32 = l>>3; s = 4p+r; h = s/121;
    // q chans = h*32 + (c%32). 8-lane-group shfl reduction -> score.
    {
        const float* kvb = kv + (size_t)b * IMG * IMG * DIM;
        const int hw = tid >> 5;         // half-wave id 0..15
        const int l  = tid & 31;
        for (int k = 0; k < 61; ++k) {
            const int T = k * 16 + hw;
            if (T < TILE * NN) {         // 968 tasks
                const int p   = T >> 3;
                const int pix = T & 7;
                const int i = p / NB, j = p - i * NB;
                const int yy = y + i - PAD, xx = x0 + pix + j - PAD;
                const int r = l >> 3;
                const int s = 4 * p + r;
                const int h = s / NN;
                float4 kq = make_float4(0.f, 0.f, 0.f, 0.f);
                if (((unsigned)yy < (unsigned)IMG) && ((unsigned)xx < (unsigned)IMG))
                    kq = *(const float4*)(kvb + ((size_t)(yy * IMG + xx)) * DIM + 4 * l);
                const float4 pv = *(const float4*)(pos + (size_t)p * DIM + 4 * l);
                const float4 qv = *(const float4*)(&qs[pix][h * 32 + 4 * (l & 7)]);
                float t = (kq.x + pv.x) * qv.x + (kq.y + pv.y) * qv.y
                        + (kq.z + pv.z) * qv.z + (kq.w + pv.w) * qv.w;
                t += __shfl_xor(t, 1, 64);
                t += __shfl_xor(t, 2, 64);
                t += __shfl_xor(t, 4, 64);
                if ((l & 7) == 0) sc[s][pix] = t;
            }
        }
    }
    __syncthreads();

    // ---- phase B: MLP. group g owns K-rows [g*121, +121), all 8 pixels ----
    // W read exactly once per block; sc via 2 broadcast ds_read_b128/iter;
    // 8 independent FMA chains.
    const int c = tid & 127;
    const int g = tid >> 7;              // 0..3
    {
        const float* wc  = w + (size_t)(g * NN) * DIM + c;
        const float* scp = &sc[g * NN][0];
        float a0 = 0.f, a1 = 0.f, a2 = 0.f, a3 = 0.f;
        float a4 = 0.f, a5 = 0.f, a6 = 0.f, a7 = 0.f;
        #pragma unroll 2
        for (int s = 0; s < NN; ++s) {
            const float wv = wc[(size_t)s * DIM];            // coalesced 256B/wave
            const float4 sA = *(const float4*)(scp + s * 8);     // broadcast
            const float4 sB = *(const float4*)(scp + s * 8 + 4); // broadcast
            a0 += sA.x * wv; a1 += sA.y * wv; a2 += sA.z * wv; a3 += sA.w * wv;
            a4 += sB.x * wv; a5 += sB.y * wv; a6 += sB.z * wv; a7 += sB.w * wv;
        }
        part[g][0][c] = a0; part[g][1][c] = a1;
        part[g][2][c] = a2; part[g][3][c] = a3;
        part[g][4][c] = a4; part[g][5][c] = a5;
        part[g][6][c] = a6; part[g][7][c] = a7;
    }
    __syncthreads();

    // ---- epilogue: reduce 4 partials, bias, exact GELU, residual ----
    for (int idx = tid; idx < TILE * DIM; idx += 512) {
        const int pix = idx >> 7, cc = idx & 127;
        float v = part[0][pix][cc] + part[1][pix][cc]
                + part[2][pix][cc] + part[3][pix][cc] + bias[cc];
        const float gl = 0.5f * v * (1.f + erff(v * 0.70710678118654752f));
        qs[pix][cc] += gl;               // x = q + gelu(mlp)
    }
    __syncthreads();

    // ---- LayerNorm: wave wid owns pixel wid (8 waves, 8 pixels) ----
    {
        const int lane = tid & 63, wid = tid >> 6;
        const float v0 = qs[wid][lane], v1 = qs[wid][lane + 64];
        float sum = v0 + v1;
        #pragma unroll
        for (int off = 1; off < 64; off <<= 1) sum += __shfl_xor(sum, off, 64);
        const float mean = sum * (1.f / 128.f);
        const float d0 = v0 - mean, d1 = v1 - mean;
        float sq = d0 * d0 + d1 * d1;
        #pragma unroll
        for (int off = 1; off < 64; off <<= 1) sq += __shfl_xor(sq, off, 64);
        const float rstd = rsqrtf(sq * (1.f / 128.f) + LN_EPS);
        float* op = out + (size_t)(pix0 + wid) * DIM;
        op[lane]      = d0 * rstd * gam[lane]      + bet[lane];
        op[lane + 64] = d1 * rstd * gam[lane + 64] + bet[lane + 64];
    }
}

extern "C" void kernel_launch(void* const* d_in, const int* in_sizes, int n_in,
                              void* d_out, int out_size, void* d_ws, size_t ws_size,
                              hipStream_t stream) {
    const float* q    = (const float*)d_in[0];
    const float* kv   = (const float*)d_in[1];
    const float* pos  = (const float*)d_in[2];
    const float* w    = (const float*)d_in[3];
    const float* bias = (const float*)d_in[4];
    const float* gam  = (const float*)d_in[5];
    const float* bet  = (const float*)d_in[6];
    float* out = (float*)d_out;

    const int n_blocks = 2 * IMG * IMG / TILE;   // 1024
    nca_kernel<<<n_blocks, 512, 0, stream>>>(q, kv, pos, w, bias, gam, bet, out);
}